// Round 1
// baseline (524.957 us; speedup 1.0000x reference)
//
#include <hip/hip_runtime.h>
#include <hip/hip_bf16.h>

// TrajectoryDecoder: B=8192 LSTM, T=128 steps, H=128, CTX=256, IN_DIM=132.
// Persistent-block design: 512 blocks x 512 threads; each block owns 16 batch
// rows for all 128 timesteps. 8 waves/block; wave w owns h-columns
// [16w,16w+16) across all 4 gates -> elementwise LSTM update is lane-local in
// MFMA D-layout (col=lane&15, row=quad*4+reg). W_hh bf16 B-frags live in VGPRs.
// h passes between steps via double-buffered LDS as bf16 hi+lo (split MFMA for
// ~fp24 effective precision). Setup GEMMs use 3-product hi/lo (near-exact).

#define HDIM 128
#define CTX_DIM 256
#define T_FRAMES 128

typedef __bf16 bf16x8 __attribute__((ext_vector_type(8)));
typedef float  f32x4  __attribute__((ext_vector_type(4)));

union frag_u {
  bf16x8 v;
  unsigned short s[8];
  uint4 u4;
};

__device__ __forceinline__ unsigned short f2bf(float x) {
  unsigned u = __builtin_bit_cast(unsigned, x);
  u += 0x7FFFu + ((u >> 16) & 1u);          // RNE to bf16
  return (unsigned short)(u >> 16);
}
__device__ __forceinline__ float bf2f(unsigned short h) {
  unsigned u = ((unsigned)h) << 16;
  return __builtin_bit_cast(float, u);
}
__device__ __forceinline__ float sigm(float x) {
  return __builtin_amdgcn_rcpf(1.f + __expf(-x));   // exp(+-inf) & rcp(inf) safe
}
__device__ __forceinline__ float tanh_f(float x) {
  return 1.f - 2.f * __builtin_amdgcn_rcpf(1.f + __expf(2.f * x));
}
template<int CTRL>
__device__ __forceinline__ float dpp_mov(float x) {
  return __builtin_bit_cast(float,
    __builtin_amdgcn_mov_dpp(__builtin_bit_cast(int, x), CTRL, 0xF, 0xF, true));
}
// sum over the 16-lane group (quad_perm xor1, xor2, then row_ror 4, 8)
__device__ __forceinline__ float row_reduce16(float v) {
  v += dpp_mov<0xB1>(v);
  v += dpp_mov<0x4E>(v);
  v += dpp_mov<0x124>(v);
  v += dpp_mov<0x128>(v);
  return v;
}

#define MFMA(a, b, c) __builtin_amdgcn_mfma_f32_16x16x32_bf16((a), (b), (c), 0, 0, 0)

__global__ __launch_bounds__(512, 2) void traj_lstm(
    const float* __restrict__ ctx, const float* __restrict__ enc,
    const float* __restrict__ ball,
    const float* __restrict__ Wh, const float* __restrict__ bh,
    const float* __restrict__ Wc, const float* __restrict__ bc,
    const float* __restrict__ W_ih, const float* __restrict__ W_hh,
    const float* __restrict__ b_ih, const float* __restrict__ b_hh,
    const float* __restrict__ Wo, const float* __restrict__ bo,
    float* __restrict__ outp)
{
  // h buffers: [buf][hi/lo][16 rows * 136 cols] bf16 (stride 136 pads banks)
  __shared__ __align__(16) unsigned short sh_h[2][2][16 * 136];
  // staging for context (stride 264) then static_in (stride 168), hi/lo
  __shared__ __align__(16) unsigned short sh_sA[16 * 264];
  __shared__ __align__(16) unsigned short sh_sB[16 * 264];
  __shared__ float sh_pw[8][32];    // per-wave pred partials [w][m*2+j]
  __shared__ float sh_pred[32];     // combined pred (= prev for next step)

  const int tid  = threadIdx.x;
  const int w    = tid >> 6;        // wave 0..7
  const int l    = tid & 63;
  const int q    = l >> 4;          // quad 0..3
  const int c16  = l & 15;
  const int colH = w * 16 + c16;    // this lane's hidden column (N index)
  const int rbase = blockIdx.x * 16;

  // ---- persistent W_hh fragments (B-operand: B[k][n] = W_hh[n][k]) ----
  frag_u Wf[4][4];                  // [gate][ktile]
  #pragma unroll
  for (int g = 0; g < 4; ++g) {
    #pragma unroll
    for (int kt = 0; kt < 4; ++kt) {
      const float* wr = W_hh + (size_t)(g * HDIM + colH) * HDIM + kt * 32 + q * 8;
      float4 f0 = *(const float4*)wr;
      float4 f1 = *(const float4*)(wr + 4);
      float ff[8] = {f0.x, f0.y, f0.z, f0.w, f1.x, f1.y, f1.z, f1.w};
      #pragma unroll
      for (int j = 0; j < 8; ++j) Wf[g][kt].s[j] = f2bf(ff[j]);
    }
  }

  // ---- stage context rows (hi/lo bf16, stride 264) ----
  for (int e = tid; e < 16 * 256; e += 512) {
    int row = e >> 8, col = e & 255;
    float x = ctx[(size_t)(rbase + row) * CTX_DIM + col];
    unsigned short hb = f2bf(x);
    sh_sA[row * 264 + col] = hb;
    sh_sB[row * 264 + col] = f2bf(x - bf2f(hb));
  }
  __syncthreads();

  // ---- h0/c0 = ctx @ Wh.T/Wc.T + bias  (3-product split, K=256) ----
  float cst[4];
  {
    f32x4 aH = {0.f, 0.f, 0.f, 0.f}, aC = {0.f, 0.f, 0.f, 0.f};
    #pragma unroll
    for (int kt = 0; kt < 8; ++kt) {
      frag_u Ahi, Alo;
      Ahi.u4 = *(const uint4*)&sh_sA[c16 * 264 + kt * 32 + q * 8];
      Alo.u4 = *(const uint4*)&sh_sB[c16 * 264 + kt * 32 + q * 8];
      frag_u bhi, blo;
      {
        const float* wr = Wh + (size_t)colH * CTX_DIM + kt * 32 + q * 8;
        float4 f0 = *(const float4*)wr;
        float4 f1 = *(const float4*)(wr + 4);
        float ff[8] = {f0.x, f0.y, f0.z, f0.w, f1.x, f1.y, f1.z, f1.w};
        #pragma unroll
        for (int j = 0; j < 8; ++j) {
          unsigned short hb = f2bf(ff[j]);
          bhi.s[j] = hb;
          blo.s[j] = f2bf(ff[j] - bf2f(hb));
        }
      }
      aH = MFMA(Ahi.v, bhi.v, aH);
      aH = MFMA(Alo.v, bhi.v, aH);
      aH = MFMA(Ahi.v, blo.v, aH);
      {
        const float* wr = Wc + (size_t)colH * CTX_DIM + kt * 32 + q * 8;
        float4 f0 = *(const float4*)wr;
        float4 f1 = *(const float4*)(wr + 4);
        float ff[8] = {f0.x, f0.y, f0.z, f0.w, f1.x, f1.y, f1.z, f1.w};
        #pragma unroll
        for (int j = 0; j < 8; ++j) {
          unsigned short hb = f2bf(ff[j]);
          bhi.s[j] = hb;
          blo.s[j] = f2bf(ff[j] - bf2f(hb));
        }
      }
      aC = MFMA(Ahi.v, bhi.v, aC);
      aC = MFMA(Alo.v, bhi.v, aC);
      aC = MFMA(Ahi.v, blo.v, aC);
    }
    float bhv = bh[colH], bcv = bc[colH];
    #pragma unroll
    for (int r = 0; r < 4; ++r) {
      float h0v = aH[r] + bhv;
      cst[r] = aC[r] + bcv;
      unsigned short hb = f2bf(h0v);
      sh_h[0][0][(q * 4 + r) * 136 + colH] = hb;                 // t=0 reads buf 0
      sh_h[0][1][(q * 4 + r) * 136 + colH] = f2bf(h0v - bf2f(hb));
    }
  }
  __syncthreads();   // protect sh_sA/B reuse

  // ---- stage static_in = [ball(2), enc(128), 0 pad] (stride 168) ----
  for (int e = tid; e < 16 * 168; e += 512) {
    int row = e / 168, col = e - row * 168;
    float x = (col < 2) ? ball[(size_t)(rbase + row) * 2 + col]
            : (col < 130) ? enc[(size_t)(rbase + row) * 128 + (col - 2)] : 0.f;
    unsigned short hb = f2bf(x);
    sh_sA[row * 168 + col] = hb;
    sh_sB[row * 168 + col] = f2bf(x - bf2f(hb));
  }
  float bo_r = 0.f;
  if (tid < 32) { sh_pred[tid] = 0.f; bo_r = bo[tid & 1]; }      // prev0 = 0
  __syncthreads();

  // ---- gate_static = static_in @ W_stat.T + b_ih + b_hh (3-product, K=160) ----
  f32x4 gacc[4] = {{0.f,0.f,0.f,0.f},{0.f,0.f,0.f,0.f},{0.f,0.f,0.f,0.f},{0.f,0.f,0.f,0.f}};
  #pragma unroll
  for (int kt = 0; kt < 5; ++kt) {
    frag_u Ahi, Alo;
    Ahi.u4 = *(const uint4*)&sh_sA[c16 * 168 + kt * 32 + q * 8];
    Alo.u4 = *(const uint4*)&sh_sB[c16 * 168 + kt * 32 + q * 8];
    #pragma unroll
    for (int g = 0; g < 4; ++g) {
      frag_u bhi, blo;
      #pragma unroll
      for (int j = 0; j < 8; ++j) {
        int kk = kt * 32 + q * 8 + j;
        float x = (kk < 130) ? W_ih[(size_t)(g * HDIM + colH) * 132 + 2 + kk] : 0.f;
        unsigned short hb = f2bf(x);
        bhi.s[j] = hb;
        blo.s[j] = f2bf(x - bf2f(hb));
      }
      gacc[g] = MFMA(Ahi.v, bhi.v, gacc[g]);
      gacc[g] = MFMA(Alo.v, bhi.v, gacc[g]);
      gacc[g] = MFMA(Ahi.v, blo.v, gacc[g]);
    }
  }
  float wp0[4], wp1[4];
  #pragma unroll
  for (int g = 0; g < 4; ++g) {
    int colG = g * HDIM + colH;
    float bb = b_ih[colG] + b_hh[colG];
    #pragma unroll
    for (int r = 0; r < 4; ++r) gacc[g][r] += bb;
    wp0[g] = W_ih[(size_t)colG * 132 + 0];
    wp1[g] = W_ih[(size_t)colG * 132 + 1];
  }
  const float wo0 = Wo[colH], wo1 = Wo[HDIM + colH];
  __syncthreads();

  // ---- time loop ----
  #pragma unroll 2
  for (int t = 0; t < T_FRAMES; ++t) {
    const int rbuf = t & 1;
    const int wbuf = rbuf ^ 1;

    // acc = gate_static + prev @ W_prev.T   (prev = last pred, lane-row m=q*4+r)
    float2 pr[4];
    #pragma unroll
    for (int r = 0; r < 4; ++r) pr[r] = *(const float2*)&sh_pred[(q * 4 + r) * 2];
    f32x4 acc[4];
    #pragma unroll
    for (int g = 0; g < 4; ++g) {
      #pragma unroll
      for (int r = 0; r < 4; ++r)
        acc[g][r] = gacc[g][r] + pr[r].x * wp0[g] + pr[r].y * wp1[g];
    }

    // gates += h @ W_hh.T  (hi+lo split A, bf16 W in regs)
    #pragma unroll
    for (int kt = 0; kt < 4; ++kt) {
      frag_u Ahi, Alo;
      Ahi.u4 = *(const uint4*)&sh_h[rbuf][0][c16 * 136 + kt * 32 + q * 8];
      Alo.u4 = *(const uint4*)&sh_h[rbuf][1][c16 * 136 + kt * 32 + q * 8];
      #pragma unroll
      for (int g = 0; g < 4; ++g) {
        acc[g] = MFMA(Ahi.v, Wf[g][kt].v, acc[g]);
        acc[g] = MFMA(Alo.v, Wf[g][kt].v, acc[g]);
      }
    }

    // elementwise LSTM update (fp32), write next h (bf16 hi/lo), pred partials
    float pp[4][2];
    #pragma unroll
    for (int r = 0; r < 4; ++r) {
      float si = sigm(acc[0][r]);
      float sf = sigm(acc[1][r]);
      float tg = tanh_f(acc[2][r]);
      float so = sigm(acc[3][r]);
      float cv = sf * cst[r] + si * tg;
      cst[r] = cv;
      float hv = so * tanh_f(cv);
      unsigned short hb = f2bf(hv);
      sh_h[wbuf][0][(q * 4 + r) * 136 + colH] = hb;
      sh_h[wbuf][1][(q * 4 + r) * 136 + colH] = f2bf(hv - bf2f(hb));
      pp[r][0] = hv * wo0;
      pp[r][1] = hv * wo1;
    }
    #pragma unroll
    for (int r = 0; r < 4; ++r) {
      pp[r][0] = row_reduce16(pp[r][0]);
      pp[r][1] = row_reduce16(pp[r][1]);
    }
    if (c16 == 0) {
      #pragma unroll
      for (int r = 0; r < 4; ++r) {
        sh_pw[w][(q * 4 + r) * 2 + 0] = pp[r][0];
        sh_pw[w][(q * 4 + r) * 2 + 1] = pp[r][1];
      }
    }
    __syncthreads();

    // combine partials -> pred; write output and feed back as prev
    if (tid < 32) {
      float s = bo_r;
      #pragma unroll
      for (int w2 = 0; w2 < 8; ++w2) s += sh_pw[w2][tid];
      sh_pred[tid] = s;
      outp[(size_t)(rbase + (tid >> 1)) * (T_FRAMES * 2) + t * 2 + (tid & 1)] = s;
    }
    __syncthreads();
  }
}

extern "C" void kernel_launch(void* const* d_in, const int* in_sizes, int n_in,
                              void* d_out, int out_size, void* d_ws, size_t ws_size,
                              hipStream_t stream) {
  (void)in_sizes; (void)n_in; (void)d_ws; (void)ws_size; (void)out_size;
  const float* ctx  = (const float*)d_in[0];
  const float* enc  = (const float*)d_in[1];
  const float* ball = (const float*)d_in[2];
  // d_in[3] = max_frames (always 128)
  const float* Wh   = (const float*)d_in[4];
  const float* bh   = (const float*)d_in[5];
  const float* Wc   = (const float*)d_in[6];
  const float* bc   = (const float*)d_in[7];
  const float* W_ih = (const float*)d_in[8];
  const float* W_hh = (const float*)d_in[9];
  const float* b_ih = (const float*)d_in[10];
  const float* b_hh = (const float*)d_in[11];
  const float* Wo   = (const float*)d_in[12];
  const float* bo   = (const float*)d_in[13];
  float* outp = (float*)d_out;

  dim3 grid(512), block(512);
  traj_lstm<<<grid, block, 0, stream>>>(ctx, enc, ball, Wh, bh, Wc, bc,
                                        W_ih, W_hh, b_ih, b_hh, Wo, bo, outp);
}

// Round 2
// 459.884 us; speedup vs baseline: 1.1415x; 1.1415x over previous
//
#include <hip/hip_runtime.h>
#include <hip/hip_bf16.h>

// TrajectoryDecoder: B=8192 LSTM, T=128, H=128, CTX=256, IN_DIM=132.
// R2: (1) rank-2 pred-feedback folded into W_eff = W_hh + wp0*wo0 + wp1*wo1
//     -> pred leaves the serial chain; ONE barrier/step; lagged pred combine.
//     (2) h passed step-to-step as bf16 hi only (halves MFMA + LDS traffic);
//     absmax headroom from R1 (1.95e-3 vs 1.09e-2 thr) covers the extra noise.
//     (3) __launch_bounds__(512,4) for 2 blocks/CU.

#define HDIM 128
#define CTX_DIM 256
#define T_FRAMES 128
#define STR 136   // h row stride (elements); multiple of 8 for b128 alignment

typedef __bf16 bf16x8 __attribute__((ext_vector_type(8)));
typedef float  f32x4  __attribute__((ext_vector_type(4)));

union frag_u {
  bf16x8 v;
  unsigned short s[8];
  uint4 u4;
};

__device__ __forceinline__ unsigned short f2bf(float x) {
  unsigned u = __builtin_bit_cast(unsigned, x);
  u += 0x7FFFu + ((u >> 16) & 1u);          // RNE to bf16
  return (unsigned short)(u >> 16);
}
__device__ __forceinline__ float bf2f(unsigned short h) {
  unsigned u = ((unsigned)h) << 16;
  return __builtin_bit_cast(float, u);
}
__device__ __forceinline__ float sigm(float x) {
  return __builtin_amdgcn_rcpf(1.f + __expf(-x));
}
__device__ __forceinline__ float tanh_f(float x) {
  return 1.f - 2.f * __builtin_amdgcn_rcpf(1.f + __expf(2.f * x));
}
template<int CTRL>
__device__ __forceinline__ float dpp_mov(float x) {
  return __builtin_bit_cast(float,
    __builtin_amdgcn_mov_dpp(__builtin_bit_cast(int, x), CTRL, 0xF, 0xF, true));
}
// sum over the 16-lane row group
__device__ __forceinline__ float row_reduce16(float v) {
  v += dpp_mov<0xB1>(v);     // quad_perm xor1
  v += dpp_mov<0x4E>(v);     // quad_perm xor2
  v += dpp_mov<0x124>(v);    // row_ror:4
  v += dpp_mov<0x128>(v);    // row_ror:8
  return v;
}

#define MFMA(a, b, c) __builtin_amdgcn_mfma_f32_16x16x32_bf16((a), (b), (c), 0, 0, 0)

__global__ __launch_bounds__(512, 4) void traj_lstm(
    const float* __restrict__ ctx, const float* __restrict__ enc,
    const float* __restrict__ ball,
    const float* __restrict__ Wh, const float* __restrict__ bh,
    const float* __restrict__ Wc, const float* __restrict__ bc,
    const float* __restrict__ W_ih, const float* __restrict__ W_hh,
    const float* __restrict__ b_ih, const float* __restrict__ b_hh,
    const float* __restrict__ Wo, const float* __restrict__ bo,
    float* __restrict__ outp)
{
  __shared__ __align__(16) __bf16 sh_h[2][16 * STR];          // h double buffer (hi only)
  __shared__ __align__(16) unsigned short sh_sA[16 * 264];    // setup staging hi
  __shared__ __align__(16) unsigned short sh_sB[16 * 264];    // setup staging lo
  __shared__ float sh_pw[2][8][32];   // per-wave pred partials, double-buffered
  __shared__ float sh_p0[32];         // virtual pred_{-1} for t=0 correction

  const int tid  = threadIdx.x;
  const int w    = tid >> 6;
  const int l    = tid & 63;
  const int q    = l >> 4;
  const int c16  = l & 15;
  const int colH = w * 16 + c16;
  const int rbase = blockIdx.x * 16;

  const float bo0 = bo[0], bo1 = bo[1];
  const float wo0 = Wo[colH], wo1 = Wo[HDIM + colH];

  // feedback weights per gate (W_prev columns)
  float wp0[4], wp1[4];
  #pragma unroll
  for (int g = 0; g < 4; ++g) {
    wp0[g] = W_ih[(size_t)(g * HDIM + colH) * 132 + 0];
    wp1[g] = W_ih[(size_t)(g * HDIM + colH) * 132 + 1];
  }

  // ---- persistent W_eff fragments: W_hh + wp0*Wo[0] + wp1*Wo[1] (bf16) ----
  frag_u Wf[4][4];                  // [gate][ktile]
  #pragma unroll
  for (int kt = 0; kt < 4; ++kt) {
    const float* w0p = Wo + kt * 32 + q * 8;
    const float* w1p = Wo + HDIM + kt * 32 + q * 8;
    float4 a0 = *(const float4*)w0p, a1 = *(const float4*)(w0p + 4);
    float4 b0 = *(const float4*)w1p, b1 = *(const float4*)(w1p + 4);
    float wo0v[8] = {a0.x, a0.y, a0.z, a0.w, a1.x, a1.y, a1.z, a1.w};
    float wo1v[8] = {b0.x, b0.y, b0.z, b0.w, b1.x, b1.y, b1.z, b1.w};
    #pragma unroll
    for (int g = 0; g < 4; ++g) {
      const float* wr = W_hh + (size_t)(g * HDIM + colH) * HDIM + kt * 32 + q * 8;
      float4 f0 = *(const float4*)wr;
      float4 f1 = *(const float4*)(wr + 4);
      float ff[8] = {f0.x, f0.y, f0.z, f0.w, f1.x, f1.y, f1.z, f1.w};
      #pragma unroll
      for (int j = 0; j < 8; ++j)
        Wf[g][kt].s[j] = f2bf(ff[j] + wp0[g] * wo0v[j] + wp1[g] * wo1v[j]);
    }
  }

  // ---- stage context rows (hi/lo bf16, stride 264) ----
  for (int e = tid; e < 16 * 256; e += 512) {
    int row = e >> 8, col = e & 255;
    float x = ctx[(size_t)(rbase + row) * CTX_DIM + col];
    unsigned short hb = f2bf(x);
    sh_sA[row * 264 + col] = hb;
    sh_sB[row * 264 + col] = f2bf(x - bf2f(hb));
  }
  __syncthreads();

  // ---- h0/c0 = ctx @ Wh.T/Wc.T + bias (3-product split, K=256) ----
  float cst[4];
  {
    f32x4 aH = {0.f, 0.f, 0.f, 0.f}, aC = {0.f, 0.f, 0.f, 0.f};
    #pragma unroll
    for (int kt = 0; kt < 8; ++kt) {
      frag_u Ahi, Alo;
      Ahi.u4 = *(const uint4*)&sh_sA[c16 * 264 + kt * 32 + q * 8];
      Alo.u4 = *(const uint4*)&sh_sB[c16 * 264 + kt * 32 + q * 8];
      frag_u bhi, blo;
      {
        const float* wr = Wh + (size_t)colH * CTX_DIM + kt * 32 + q * 8;
        float4 f0 = *(const float4*)wr;
        float4 f1 = *(const float4*)(wr + 4);
        float ff[8] = {f0.x, f0.y, f0.z, f0.w, f1.x, f1.y, f1.z, f1.w};
        #pragma unroll
        for (int j = 0; j < 8; ++j) {
          unsigned short hb = f2bf(ff[j]);
          bhi.s[j] = hb;
          blo.s[j] = f2bf(ff[j] - bf2f(hb));
        }
      }
      aH = MFMA(Ahi.v, bhi.v, aH);
      aH = MFMA(Alo.v, bhi.v, aH);
      aH = MFMA(Ahi.v, blo.v, aH);
      {
        const float* wr = Wc + (size_t)colH * CTX_DIM + kt * 32 + q * 8;
        float4 f0 = *(const float4*)wr;
        float4 f1 = *(const float4*)(wr + 4);
        float ff[8] = {f0.x, f0.y, f0.z, f0.w, f1.x, f1.y, f1.z, f1.w};
        #pragma unroll
        for (int j = 0; j < 8; ++j) {
          unsigned short hb = f2bf(ff[j]);
          bhi.s[j] = hb;
          blo.s[j] = f2bf(ff[j] - bf2f(hb));
        }
      }
      aC = MFMA(Ahi.v, bhi.v, aC);
      aC = MFMA(Alo.v, bhi.v, aC);
      aC = MFMA(Ahi.v, blo.v, aC);
    }
    float bhv = bh[colH], bcv = bc[colH];
    float pp0[4][2];
    #pragma unroll
    for (int r = 0; r < 4; ++r) {
      float h0v = aH[r] + bhv;
      cst[r] = aC[r] + bcv;
      sh_h[0][(q * 4 + r) * STR + colH] = (__bf16)h0v;
      pp0[r][0] = h0v * wo0;
      pp0[r][1] = h0v * wo1;
    }
    #pragma unroll
    for (int r = 0; r < 4; ++r) {
      pp0[r][0] = row_reduce16(pp0[r][0]);
      pp0[r][1] = row_reduce16(pp0[r][1]);
    }
    if (c16 == 0) {
      #pragma unroll
      for (int r = 0; r < 4; ++r) {
        sh_pw[0][w][(q * 4 + r) * 2 + 0] = pp0[r][0];
        sh_pw[0][w][(q * 4 + r) * 2 + 1] = pp0[r][1];
      }
    }
  }
  __syncthreads();   // sA/sB reuse + pw[0] visibility

  // ---- stage static_in = [ball(2), enc(128), pad] (stride 168) ----
  for (int e = tid; e < 16 * 168; e += 512) {
    int row = e / 168, col = e - row * 168;
    float x = (col < 2) ? ball[(size_t)(rbase + row) * 2 + col]
            : (col < 130) ? enc[(size_t)(rbase + row) * 128 + (col - 2)] : 0.f;
    unsigned short hb = f2bf(x);
    sh_sA[row * 168 + col] = hb;
    sh_sB[row * 168 + col] = f2bf(x - bf2f(hb));
  }
  // combine virtual pred_{-1} = h0 @ Wo.T + bo (for t=0 feedback correction)
  if (tid < 32) {
    float s = (tid & 1) ? bo1 : bo0;
    #pragma unroll
    for (int w2 = 0; w2 < 8; ++w2) s += sh_pw[0][w2][tid];
    sh_p0[tid] = s;
  }
  __syncthreads();

  // ---- gate_static (3-product, K=160) + biases + bo-feedback fold ----
  f32x4 gacc[4] = {{0.f,0.f,0.f,0.f},{0.f,0.f,0.f,0.f},{0.f,0.f,0.f,0.f},{0.f,0.f,0.f,0.f}};
  #pragma unroll
  for (int kt = 0; kt < 5; ++kt) {
    frag_u Ahi, Alo;
    Ahi.u4 = *(const uint4*)&sh_sA[c16 * 168 + kt * 32 + q * 8];
    Alo.u4 = *(const uint4*)&sh_sB[c16 * 168 + kt * 32 + q * 8];
    #pragma unroll
    for (int g = 0; g < 4; ++g) {
      frag_u bhi, blo;
      #pragma unroll
      for (int j = 0; j < 8; ++j) {
        int kk = kt * 32 + q * 8 + j;
        float x = (kk < 130) ? W_ih[(size_t)(g * HDIM + colH) * 132 + 2 + kk] : 0.f;
        unsigned short hb = f2bf(x);
        bhi.s[j] = hb;
        blo.s[j] = f2bf(x - bf2f(hb));
      }
      gacc[g] = MFMA(Ahi.v, bhi.v, gacc[g]);
      gacc[g] = MFMA(Alo.v, bhi.v, gacc[g]);
      gacc[g] = MFMA(Ahi.v, blo.v, gacc[g]);
    }
  }
  f32x4 corrv[4];
  {
    float2 p0r[4];
    #pragma unroll
    for (int r = 0; r < 4; ++r) p0r[r] = *(const float2*)&sh_p0[(q * 4 + r) * 2];
    #pragma unroll
    for (int g = 0; g < 4; ++g) {
      int colG = g * HDIM + colH;
      float bb = b_ih[colG] + b_hh[colG] + bo0 * wp0[g] + bo1 * wp1[g];
      #pragma unroll
      for (int r = 0; r < 4; ++r) {
        gacc[g][r] += bb;
        corrv[g][r] = p0r[r].x * wp0[g] + p0r[r].y * wp1[g];  // t=0 only
      }
    }
  }
  // no barrier needed: loop never writes sA/sB; pw[0] combine already done.

  // ---- time loop: ONE barrier per step ----
  auto body = [&](int t, int rbuf, int wbuf, bool first) {
    frag_u A[4];
    const __bf16* hp = &sh_h[rbuf][c16 * STR];
    #pragma unroll
    for (int kt = 0; kt < 4; ++kt)
      A[kt].u4 = *(const uint4*)(hp + kt * 32 + q * 8);

    f32x4 acc[4];
    #pragma unroll
    for (int g = 0; g < 4; ++g) {
      f32x4 c0 = gacc[g];
      if (first) {
        #pragma unroll
        for (int r = 0; r < 4; ++r) c0[r] -= corrv[g][r];
      }
      acc[g] = MFMA(A[0].v, Wf[g][0].v, c0);
      #pragma unroll
      for (int kt = 1; kt < 4; ++kt)
        acc[g] = MFMA(A[kt].v, Wf[g][kt].v, acc[g]);
    }

    __bf16* hw = &sh_h[wbuf][colH];
    float pp[4][2];
    #pragma unroll
    for (int r = 0; r < 4; ++r) {
      float si = sigm(acc[0][r]);
      float sf = sigm(acc[1][r]);
      float tg = tanh_f(acc[2][r]);
      float so = sigm(acc[3][r]);
      float cv = sf * cst[r] + si * tg;
      cst[r] = cv;
      float hv = so * tanh_f(cv);
      hw[(q * 4 + r) * STR] = (__bf16)hv;
      pp[r][0] = hv * wo0;
      pp[r][1] = hv * wo1;
    }
    #pragma unroll
    for (int r = 0; r < 4; ++r) {
      pp[r][0] = row_reduce16(pp[r][0]);
      pp[r][1] = row_reduce16(pp[r][1]);
    }
    if (c16 == 0) {
      #pragma unroll
      for (int r = 0; r < 4; ++r) {
        sh_pw[rbuf][w][(q * 4 + r) * 2 + 0] = pp[r][0];
        sh_pw[rbuf][w][(q * 4 + r) * 2 + 1] = pp[r][1];
      }
    }
    // lagged combine of pred[t-1] (rotating wave; reads pw[(t-1)&1] == pw[wbuf])
    if (!first && w == (t & 7) && l < 32) {
      float s = (l & 1) ? bo1 : bo0;
      #pragma unroll
      for (int w2 = 0; w2 < 8; ++w2) s += sh_pw[wbuf][w2][l];
      outp[(size_t)(rbase + (l >> 1)) * (T_FRAMES * 2) + (t - 1) * 2 + (l & 1)] = s;
    }
    __syncthreads();
  };

  body(0, 0, 1, true);
  for (int tp = 0; tp < 63; ++tp) {
    body(2 * tp + 1, 1, 0, false);
    body(2 * tp + 2, 0, 1, false);
  }
  body(127, 1, 0, false);

  // final pred (t=127) sits in pw[1]
  if (tid < 32) {
    float s = (tid & 1) ? bo1 : bo0;
    #pragma unroll
    for (int w2 = 0; w2 < 8; ++w2) s += sh_pw[1][w2][tid];
    outp[(size_t)(rbase + (tid >> 1)) * (T_FRAMES * 2) + 127 * 2 + (tid & 1)] = s;
  }
}

extern "C" void kernel_launch(void* const* d_in, const int* in_sizes, int n_in,
                              void* d_out, int out_size, void* d_ws, size_t ws_size,
                              hipStream_t stream) {
  (void)in_sizes; (void)n_in; (void)d_ws; (void)ws_size; (void)out_size;
  const float* ctx  = (const float*)d_in[0];
  const float* enc  = (const float*)d_in[1];
  const float* ball = (const float*)d_in[2];
  // d_in[3] = max_frames (always 128)
  const float* Wh   = (const float*)d_in[4];
  const float* bh   = (const float*)d_in[5];
  const float* Wc   = (const float*)d_in[6];
  const float* bc   = (const float*)d_in[7];
  const float* W_ih = (const float*)d_in[8];
  const float* W_hh = (const float*)d_in[9];
  const float* b_ih = (const float*)d_in[10];
  const float* b_hh = (const float*)d_in[11];
  const float* Wo   = (const float*)d_in[12];
  const float* bo   = (const float*)d_in[13];
  float* outp = (float*)d_out;

  dim3 grid(512), block(512);
  traj_lstm<<<grid, block, 0, stream>>>(ctx, enc, ball, Wh, bh, Wc, bc,
                                        W_ih, W_hh, b_ih, b_hh, Wo, bo, outp);
}

// Round 4
// 429.169 us; speedup vs baseline: 1.2232x; 1.0716x over previous
//
#include <hip/hip_runtime.h>
#include <hip/hip_bf16.h>

// TrajectoryDecoder: B=8192 LSTM, T=128, H=128, CTX=256, IN_DIM=132.
// R4 = R2's PROVEN dataflow (rank-2 pred feedback folded into W_eff, one
// barrier/step, DPP lag-1 pred combine) + three register/spill fixes:
//  - __launch_bounds__(512,2): empirically arg2 acts like blocks/CU on this
//    toolchain (R2's (512,4) gave a 64-VGPR cap + 330 MB spill traffic).
//  - gate_static moved to LDS ([g][tid] f32x4 private slots): -16 VGPRs.
//  - A-fragments streamed one-at-a-time in the kt loop: -8 VGPRs.
// Target: no scratch spills, 2 blocks/CU resident.

#define HDIM 128
#define CTX_DIM 256
#define T_FRAMES 128
#define STR 136   // h row stride (elements); 272B rows keep 16B alignment

typedef __bf16 bf16x8 __attribute__((ext_vector_type(8)));
typedef float  f32x4  __attribute__((ext_vector_type(4)));

union frag_u {
  bf16x8 v;
  unsigned short s[8];
  uint4 u4;
};

__device__ __forceinline__ unsigned short f2bf(float x) {
  unsigned u = __builtin_bit_cast(unsigned, x);
  u += 0x7FFFu + ((u >> 16) & 1u);          // RNE to bf16
  return (unsigned short)(u >> 16);
}
__device__ __forceinline__ float bf2f(unsigned short h) {
  unsigned u = ((unsigned)h) << 16;
  return __builtin_bit_cast(float, u);
}
__device__ __forceinline__ float sigm(float x) {
  return __builtin_amdgcn_rcpf(1.f + __expf(-x));
}
__device__ __forceinline__ float tanh_f(float x) {
  return 1.f - 2.f * __builtin_amdgcn_rcpf(1.f + __expf(2.f * x));
}
template<int CTRL>
__device__ __forceinline__ float dpp_mov(float x) {
  return __builtin_bit_cast(float,
    __builtin_amdgcn_mov_dpp(__builtin_bit_cast(int, x), CTRL, 0xF, 0xF, true));
}
// sum over the 16-lane row group
__device__ __forceinline__ float row_reduce16(float v) {
  v += dpp_mov<0xB1>(v);     // quad_perm xor1
  v += dpp_mov<0x4E>(v);     // quad_perm xor2
  v += dpp_mov<0x124>(v);    // row_ror:4
  v += dpp_mov<0x128>(v);    // row_ror:8
  return v;
}

#define MFMA(a, b, c) __builtin_amdgcn_mfma_f32_16x16x32_bf16((a), (b), (c), 0, 0, 0)

__global__ __launch_bounds__(512, 2) void traj_lstm(
    const float* __restrict__ ctx, const float* __restrict__ enc,
    const float* __restrict__ ball,
    const float* __restrict__ Wh, const float* __restrict__ bh,
    const float* __restrict__ Wc, const float* __restrict__ bc,
    const float* __restrict__ W_ih, const float* __restrict__ W_hh,
    const float* __restrict__ b_ih, const float* __restrict__ b_hh,
    const float* __restrict__ Wo, const float* __restrict__ bo,
    float* __restrict__ outp)
{
  __shared__ __align__(16) __bf16 sh_h[2][16 * STR];          // h double buffer
  __shared__ __align__(16) unsigned short sh_sA[16 * 264];    // setup staging hi
  __shared__ __align__(16) unsigned short sh_sB[16 * 264];    // setup staging lo
  __shared__ __align__(16) f32x4 sh_g4[4][512];               // gate_static per lane
  __shared__ float sh_pw[2][8][32];   // per-wave pred partials, double-buffered
  __shared__ float sh_p0[32];         // virtual pred_{-1} for t=0 correction

  const int tid  = threadIdx.x;
  const int w    = tid >> 6;
  const int l    = tid & 63;
  const int q    = l >> 4;
  const int c16  = l & 15;
  const int colH = w * 16 + c16;
  const int rbase = blockIdx.x * 16;

  const float bo0 = bo[0], bo1 = bo[1];
  const float wo0 = Wo[colH], wo1 = Wo[HDIM + colH];

  // feedback weights per gate (W_prev columns)
  float wp0[4], wp1[4];
  #pragma unroll
  for (int g = 0; g < 4; ++g) {
    wp0[g] = W_ih[(size_t)(g * HDIM + colH) * 132 + 0];
    wp1[g] = W_ih[(size_t)(g * HDIM + colH) * 132 + 1];
  }

  // ---- persistent W_eff fragments: W_hh + wp0*Wo[0] + wp1*Wo[1] (bf16) ----
  frag_u Wf[4][4];                  // [gate][ktile]
  #pragma unroll
  for (int kt = 0; kt < 4; ++kt) {
    const float* w0p = Wo + kt * 32 + q * 8;
    const float* w1p = Wo + HDIM + kt * 32 + q * 8;
    float4 a0 = *(const float4*)w0p, a1 = *(const float4*)(w0p + 4);
    float4 b0 = *(const float4*)w1p, b1 = *(const float4*)(w1p + 4);
    float wo0v[8] = {a0.x, a0.y, a0.z, a0.w, a1.x, a1.y, a1.z, a1.w};
    float wo1v[8] = {b0.x, b0.y, b0.z, b0.w, b1.x, b1.y, b1.z, b1.w};
    #pragma unroll
    for (int g = 0; g < 4; ++g) {
      const float* wr = W_hh + (size_t)(g * HDIM + colH) * HDIM + kt * 32 + q * 8;
      float4 f0 = *(const float4*)wr;
      float4 f1 = *(const float4*)(wr + 4);
      float ff[8] = {f0.x, f0.y, f0.z, f0.w, f1.x, f1.y, f1.z, f1.w};
      #pragma unroll
      for (int j = 0; j < 8; ++j)
        Wf[g][kt].s[j] = f2bf(ff[j] + wp0[g] * wo0v[j] + wp1[g] * wo1v[j]);
    }
  }

  // ---- stage context rows (hi/lo bf16, stride 264) ----
  for (int e = tid; e < 16 * 256; e += 512) {
    int row = e >> 8, col = e & 255;
    float x = ctx[(size_t)(rbase + row) * CTX_DIM + col];
    unsigned short hb = f2bf(x);
    sh_sA[row * 264 + col] = hb;
    sh_sB[row * 264 + col] = f2bf(x - bf2f(hb));
  }
  __syncthreads();

  // ---- h0/c0 = ctx @ Wh.T/Wc.T + bias (3-product split, K=256) ----
  float cst[4];
  {
    f32x4 aH = {0.f, 0.f, 0.f, 0.f}, aC = {0.f, 0.f, 0.f, 0.f};
    #pragma unroll
    for (int kt = 0; kt < 8; ++kt) {
      frag_u Ahi, Alo;
      Ahi.u4 = *(const uint4*)&sh_sA[c16 * 264 + kt * 32 + q * 8];
      Alo.u4 = *(const uint4*)&sh_sB[c16 * 264 + kt * 32 + q * 8];
      frag_u bhi, blo;
      {
        const float* wr = Wh + (size_t)colH * CTX_DIM + kt * 32 + q * 8;
        float4 f0 = *(const float4*)wr;
        float4 f1 = *(const float4*)(wr + 4);
        float ff[8] = {f0.x, f0.y, f0.z, f0.w, f1.x, f1.y, f1.z, f1.w};
        #pragma unroll
        for (int j = 0; j < 8; ++j) {
          unsigned short hb = f2bf(ff[j]);
          bhi.s[j] = hb;
          blo.s[j] = f2bf(ff[j] - bf2f(hb));
        }
      }
      aH = MFMA(Ahi.v, bhi.v, aH);
      aH = MFMA(Alo.v, bhi.v, aH);
      aH = MFMA(Ahi.v, blo.v, aH);
      {
        const float* wr = Wc + (size_t)colH * CTX_DIM + kt * 32 + q * 8;
        float4 f0 = *(const float4*)wr;
        float4 f1 = *(const float4*)(wr + 4);
        float ff[8] = {f0.x, f0.y, f0.z, f0.w, f1.x, f1.y, f1.z, f1.w};
        #pragma unroll
        for (int j = 0; j < 8; ++j) {
          unsigned short hb = f2bf(ff[j]);
          bhi.s[j] = hb;
          blo.s[j] = f2bf(ff[j] - bf2f(hb));
        }
      }
      aC = MFMA(Ahi.v, bhi.v, aC);
      aC = MFMA(Alo.v, bhi.v, aC);
      aC = MFMA(Ahi.v, blo.v, aC);
    }
    float bhv = bh[colH], bcv = bc[colH];
    float pp0[4][2];
    #pragma unroll
    for (int r = 0; r < 4; ++r) {
      float h0v = aH[r] + bhv;
      cst[r] = aC[r] + bcv;
      sh_h[0][(q * 4 + r) * STR + colH] = (__bf16)h0v;
      pp0[r][0] = h0v * wo0;
      pp0[r][1] = h0v * wo1;
    }
    #pragma unroll
    for (int r = 0; r < 4; ++r) {
      pp0[r][0] = row_reduce16(pp0[r][0]);
      pp0[r][1] = row_reduce16(pp0[r][1]);
    }
    if (c16 == 0) {
      #pragma unroll
      for (int r = 0; r < 4; ++r) {
        sh_pw[0][w][(q * 4 + r) * 2 + 0] = pp0[r][0];
        sh_pw[0][w][(q * 4 + r) * 2 + 1] = pp0[r][1];
      }
    }
  }
  __syncthreads();   // sA/sB reuse + pw[0] visibility

  // ---- stage static_in = [ball(2), enc(128), pad] (stride 168) ----
  for (int e = tid; e < 16 * 168; e += 512) {
    int row = e / 168, col = e - row * 168;
    float x = (col < 2) ? ball[(size_t)(rbase + row) * 2 + col]
            : (col < 130) ? enc[(size_t)(rbase + row) * 128 + (col - 2)] : 0.f;
    unsigned short hb = f2bf(x);
    sh_sA[row * 168 + col] = hb;
    sh_sB[row * 168 + col] = f2bf(x - bf2f(hb));
  }
  // virtual pred_{-1} = h0 @ Wo.T + bo (t=0 feedback correction)
  if (tid < 32) {
    float s = (tid & 1) ? bo1 : bo0;
    #pragma unroll
    for (int w2 = 0; w2 < 8; ++w2) s += sh_pw[0][w2][tid];
    sh_p0[tid] = s;
  }
  __syncthreads();

  // ---- gate_static (3-product, K=160) + biases + bo-feedback fold -> LDS ----
  {
    f32x4 gacc[4] = {{0.f,0.f,0.f,0.f},{0.f,0.f,0.f,0.f},{0.f,0.f,0.f,0.f},{0.f,0.f,0.f,0.f}};
    #pragma unroll
    for (int kt = 0; kt < 5; ++kt) {
      frag_u Ahi, Alo;
      Ahi.u4 = *(const uint4*)&sh_sA[c16 * 168 + kt * 32 + q * 8];
      Alo.u4 = *(const uint4*)&sh_sB[c16 * 168 + kt * 32 + q * 8];
      #pragma unroll
      for (int g = 0; g < 4; ++g) {
        frag_u bhi, blo;
        #pragma unroll
        for (int j = 0; j < 8; ++j) {
          int kk = kt * 32 + q * 8 + j;
          float x = (kk < 130) ? W_ih[(size_t)(g * HDIM + colH) * 132 + 2 + kk] : 0.f;
          unsigned short hb = f2bf(x);
          bhi.s[j] = hb;
          blo.s[j] = f2bf(x - bf2f(hb));
        }
        gacc[g] = MFMA(Ahi.v, bhi.v, gacc[g]);
        gacc[g] = MFMA(Alo.v, bhi.v, gacc[g]);
        gacc[g] = MFMA(Ahi.v, blo.v, gacc[g]);
      }
    }
    #pragma unroll
    for (int g = 0; g < 4; ++g) {
      int colG = g * HDIM + colH;
      float bb = b_ih[colG] + b_hh[colG] + bo0 * wp0[g] + bo1 * wp1[g];
      #pragma unroll
      for (int r = 0; r < 4; ++r) gacc[g][r] += bb;
      sh_g4[g][tid] = gacc[g];          // per-lane private slot
    }
  }

  // t=0 correction (prev0 = 0): subtract p0-driven feedback in peeled iter
  f32x4 corrv[4];
  {
    float2 p0r[4];
    #pragma unroll
    for (int r = 0; r < 4; ++r) p0r[r] = *(const float2*)&sh_p0[(q * 4 + r) * 2];
    #pragma unroll
    for (int g = 0; g < 4; ++g) {
      #pragma unroll
      for (int r = 0; r < 4; ++r)
        corrv[g][r] = p0r[r].x * wp0[g] + p0r[r].y * wp1[g];
    }
  }

  // ---- time loop: ONE barrier per step (R2's proven scheme) ----
  auto body = [&](int t, int rbuf, bool first) {
    const int wbuf = rbuf ^ 1;

    f32x4 acc[4];
    #pragma unroll
    for (int g = 0; g < 4; ++g) {
      acc[g] = sh_g4[g][tid];
      if (first) {
        #pragma unroll
        for (int r = 0; r < 4; ++r) acc[g][r] -= corrv[g][r];
      }
    }

    // gates += h @ W_eff.T  (streamed A-frags)
    const __bf16* hp = &sh_h[rbuf][c16 * STR];
    #pragma unroll
    for (int kt = 0; kt < 4; ++kt) {
      frag_u A;
      A.u4 = *(const uint4*)(hp + kt * 32 + q * 8);
      #pragma unroll
      for (int g = 0; g < 4; ++g)
        acc[g] = MFMA(A.v, Wf[g][kt].v, acc[g]);
    }

    // elementwise LSTM update; write next h (bf16); pred partials via DPP
    __bf16* hw = &sh_h[wbuf][colH];
    float pp[4][2];
    #pragma unroll
    for (int r = 0; r < 4; ++r) {
      float si = sigm(acc[0][r]);
      float sf = sigm(acc[1][r]);
      float tg = tanh_f(acc[2][r]);
      float so = sigm(acc[3][r]);
      float cv = sf * cst[r] + si * tg;
      cst[r] = cv;
      float hv = so * tanh_f(cv);
      hw[(q * 4 + r) * STR] = (__bf16)hv;
      pp[r][0] = hv * wo0;
      pp[r][1] = hv * wo1;
    }
    #pragma unroll
    for (int r = 0; r < 4; ++r) {
      pp[r][0] = row_reduce16(pp[r][0]);
      pp[r][1] = row_reduce16(pp[r][1]);
    }
    if (c16 == 0) {
      #pragma unroll
      for (int r = 0; r < 4; ++r) {
        sh_pw[rbuf][w][(q * 4 + r) * 2 + 0] = pp[r][0];
        sh_pw[rbuf][w][(q * 4 + r) * 2 + 1] = pp[r][1];
      }
    }
    // lagged combine of pred[t-1] (rotating wave; reads pw[wbuf] = prev step's)
    if (!first && w == (t & 7) && l < 32) {
      float s = (l & 1) ? bo1 : bo0;
      #pragma unroll
      for (int w2 = 0; w2 < 8; ++w2) s += sh_pw[wbuf][w2][l];
      outp[(size_t)(rbase + (l >> 1)) * (T_FRAMES * 2) + (t - 1) * 2 + (l & 1)] = s;
    }
    __syncthreads();
  };

  body(0, 0, true);    // reads h0 (buf0), writes buf1
  for (int tp = 0; tp < 63; ++tp) {
    body(2 * tp + 1, 1, false);
    body(2 * tp + 2, 0, false);
  }
  body(127, 1, false);

  // final pred (t=127) sits in pw[1]
  if (tid < 32) {
    float s = (tid & 1) ? bo1 : bo0;
    #pragma unroll
    for (int w2 = 0; w2 < 8; ++w2) s += sh_pw[1][w2][tid];
    outp[(size_t)(rbase + (tid >> 1)) * (T_FRAMES * 2) + 127 * 2 + (tid & 1)] = s;
  }
}

extern "C" void kernel_launch(void* const* d_in, const int* in_sizes, int n_in,
                              void* d_out, int out_size, void* d_ws, size_t ws_size,
                              hipStream_t stream) {
  (void)in_sizes; (void)n_in; (void)d_ws; (void)ws_size; (void)out_size;
  const float* ctx  = (const float*)d_in[0];
  const float* enc  = (const float*)d_in[1];
  const float* ball = (const float*)d_in[2];
  // d_in[3] = max_frames (always 128)
  const float* Wh   = (const float*)d_in[4];
  const float* bh   = (const float*)d_in[5];
  const float* Wc   = (const float*)d_in[6];
  const float* bc   = (const float*)d_in[7];
  const float* W_ih = (const float*)d_in[8];
  const float* W_hh = (const float*)d_in[9];
  const float* b_ih = (const float*)d_in[10];
  const float* b_hh = (const float*)d_in[11];
  const float* Wo   = (const float*)d_in[12];
  const float* bo   = (const float*)d_in[13];
  float* outp = (float*)d_out;

  dim3 grid(512), block(512);
  traj_lstm<<<grid, block, 0, stream>>>(ctx, enc, ball, Wh, bh, Wc, bc,
                                        W_ih, W_hh, b_ih, b_hh, Wo, bo, outp);
}

// Round 5
// 384.461 us; speedup vs baseline: 1.3654x; 1.1163x over previous
//
#include <hip/hip_runtime.h>
#include <hip/hip_bf16.h>

// TrajectoryDecoder: B=8192 LSTM, T=128, H=128, CTX=256, IN_DIM=132.
// R5: BB=32 rows/block, grid=256 (1 block/CU), __launch_bounds__(512,1)
//     -> 256-VGPR budget (2 waves/SIMD): gate_static back in REGISTERS
//        (no per-step LDS read), acc initialized via MFMA C-operand (no movs),
//        2 independent row-tiles per wave (2x ILP), barrier amortized 2x,
//        weight HBM fetch halved. Numerics identical to R4 (absmax 2.9e-3).

#define HDIM 128
#define CTX_DIM 256
#define T_FRAMES 128
#define BB 32     // batch rows per block
#define STR 136   // h row stride (elements); 272B rows keep 16B alignment

typedef __bf16 bf16x8 __attribute__((ext_vector_type(8)));
typedef float  f32x4  __attribute__((ext_vector_type(4)));

union frag_u {
  bf16x8 v;
  unsigned short s[8];
  uint4 u4;
};

__device__ __forceinline__ unsigned short f2bf(float x) {
  unsigned u = __builtin_bit_cast(unsigned, x);
  u += 0x7FFFu + ((u >> 16) & 1u);          // RNE to bf16
  return (unsigned short)(u >> 16);
}
__device__ __forceinline__ float bf2f(unsigned short h) {
  unsigned u = ((unsigned)h) << 16;
  return __builtin_bit_cast(float, u);
}
__device__ __forceinline__ float sigm(float x) {
  return __builtin_amdgcn_rcpf(1.f + __expf(-x));
}
__device__ __forceinline__ float tanh_f(float x) {
  return 1.f - 2.f * __builtin_amdgcn_rcpf(1.f + __expf(2.f * x));
}
template<int CTRL>
__device__ __forceinline__ float dpp_mov(float x) {
  return __builtin_bit_cast(float,
    __builtin_amdgcn_mov_dpp(__builtin_bit_cast(int, x), CTRL, 0xF, 0xF, true));
}
// sum over the 16-lane row group
__device__ __forceinline__ float row_reduce16(float v) {
  v += dpp_mov<0xB1>(v);     // quad_perm xor1
  v += dpp_mov<0x4E>(v);     // quad_perm xor2
  v += dpp_mov<0x124>(v);    // row_ror:4
  v += dpp_mov<0x128>(v);    // row_ror:8
  return v;
}

#define MFMA(a, b, c) __builtin_amdgcn_mfma_f32_16x16x32_bf16((a), (b), (c), 0, 0, 0)

__global__ __launch_bounds__(512, 1) void traj_lstm(
    const float* __restrict__ ctx, const float* __restrict__ enc,
    const float* __restrict__ ball,
    const float* __restrict__ Wh, const float* __restrict__ bh,
    const float* __restrict__ Wc, const float* __restrict__ bc,
    const float* __restrict__ W_ih, const float* __restrict__ W_hh,
    const float* __restrict__ b_ih, const float* __restrict__ b_hh,
    const float* __restrict__ Wo, const float* __restrict__ bo,
    float* __restrict__ outp)
{
  __shared__ __align__(16) __bf16 sh_h[2][BB * STR];          // h double buffer (17.4 KB)
  __shared__ __align__(16) unsigned short sh_sA[BB * 264];    // setup staging hi (16.9 KB)
  __shared__ __align__(16) unsigned short sh_sB[BB * 264];    // setup staging lo (16.9 KB)
  __shared__ float sh_pw[2][8][BB * 2];   // per-wave pred partials (4 KB)
  __shared__ float sh_p0[BB * 2];         // virtual pred_{-1} for t=0 correction

  const int tid  = threadIdx.x;
  const int w    = tid >> 6;
  const int l    = tid & 63;
  const int q    = l >> 4;
  const int c16  = l & 15;
  const int colH = w * 16 + c16;
  const int rbase = blockIdx.x * BB;

  const float bo0 = bo[0], bo1 = bo[1];
  const float wo0 = Wo[colH], wo1 = Wo[HDIM + colH];

  // feedback weights per gate (W_prev columns)
  float wp0[4], wp1[4];
  #pragma unroll
  for (int g = 0; g < 4; ++g) {
    wp0[g] = W_ih[(size_t)(g * HDIM + colH) * 132 + 0];
    wp1[g] = W_ih[(size_t)(g * HDIM + colH) * 132 + 1];
  }

  // ---- persistent W_eff fragments: W_hh + wp0*Wo[0] + wp1*Wo[1] (bf16) ----
  frag_u Wf[4][4];                  // [gate][ktile]
  #pragma unroll
  for (int kt = 0; kt < 4; ++kt) {
    const float* w0p = Wo + kt * 32 + q * 8;
    const float* w1p = Wo + HDIM + kt * 32 + q * 8;
    float4 a0 = *(const float4*)w0p, a1 = *(const float4*)(w0p + 4);
    float4 b0 = *(const float4*)w1p, b1 = *(const float4*)(w1p + 4);
    float wo0v[8] = {a0.x, a0.y, a0.z, a0.w, a1.x, a1.y, a1.z, a1.w};
    float wo1v[8] = {b0.x, b0.y, b0.z, b0.w, b1.x, b1.y, b1.z, b1.w};
    #pragma unroll
    for (int g = 0; g < 4; ++g) {
      const float* wr = W_hh + (size_t)(g * HDIM + colH) * HDIM + kt * 32 + q * 8;
      float4 f0 = *(const float4*)wr;
      float4 f1 = *(const float4*)(wr + 4);
      float ff[8] = {f0.x, f0.y, f0.z, f0.w, f1.x, f1.y, f1.z, f1.w};
      #pragma unroll
      for (int j = 0; j < 8; ++j)
        Wf[g][kt].s[j] = f2bf(ff[j] + wp0[g] * wo0v[j] + wp1[g] * wo1v[j]);
    }
  }

  // ---- stage context rows (32 rows, hi/lo bf16, stride 264) ----
  for (int e = tid; e < BB * 256; e += 512) {
    int row = e >> 8, col = e & 255;
    float x = ctx[(size_t)(rbase + row) * CTX_DIM + col];
    unsigned short hb = f2bf(x);
    sh_sA[row * 264 + col] = hb;
    sh_sB[row * 264 + col] = f2bf(x - bf2f(hb));
  }
  __syncthreads();

  // ---- h0/c0 = ctx @ Wh.T/Wc.T + bias (3-product split, K=256, 2 row-tiles) ----
  float cst[8];   // [rt*4 + r]
  {
    f32x4 aH[2] = {{0.f,0.f,0.f,0.f},{0.f,0.f,0.f,0.f}};
    f32x4 aC[2] = {{0.f,0.f,0.f,0.f},{0.f,0.f,0.f,0.f}};
    #pragma unroll
    for (int kt = 0; kt < 8; ++kt) {
      frag_u Ahi[2], Alo[2];
      #pragma unroll
      for (int rt = 0; rt < 2; ++rt) {
        Ahi[rt].u4 = *(const uint4*)&sh_sA[(rt * 16 + c16) * 264 + kt * 32 + q * 8];
        Alo[rt].u4 = *(const uint4*)&sh_sB[(rt * 16 + c16) * 264 + kt * 32 + q * 8];
      }
      frag_u bhi, blo;
      {
        const float* wr = Wh + (size_t)colH * CTX_DIM + kt * 32 + q * 8;
        float4 f0 = *(const float4*)wr;
        float4 f1 = *(const float4*)(wr + 4);
        float ff[8] = {f0.x, f0.y, f0.z, f0.w, f1.x, f1.y, f1.z, f1.w};
        #pragma unroll
        for (int j = 0; j < 8; ++j) {
          unsigned short hb = f2bf(ff[j]);
          bhi.s[j] = hb;
          blo.s[j] = f2bf(ff[j] - bf2f(hb));
        }
      }
      #pragma unroll
      for (int rt = 0; rt < 2; ++rt) {
        aH[rt] = MFMA(Ahi[rt].v, bhi.v, aH[rt]);
        aH[rt] = MFMA(Alo[rt].v, bhi.v, aH[rt]);
        aH[rt] = MFMA(Ahi[rt].v, blo.v, aH[rt]);
      }
      {
        const float* wr = Wc + (size_t)colH * CTX_DIM + kt * 32 + q * 8;
        float4 f0 = *(const float4*)wr;
        float4 f1 = *(const float4*)(wr + 4);
        float ff[8] = {f0.x, f0.y, f0.z, f0.w, f1.x, f1.y, f1.z, f1.w};
        #pragma unroll
        for (int j = 0; j < 8; ++j) {
          unsigned short hb = f2bf(ff[j]);
          bhi.s[j] = hb;
          blo.s[j] = f2bf(ff[j] - bf2f(hb));
        }
      }
      #pragma unroll
      for (int rt = 0; rt < 2; ++rt) {
        aC[rt] = MFMA(Ahi[rt].v, bhi.v, aC[rt]);
        aC[rt] = MFMA(Alo[rt].v, bhi.v, aC[rt]);
        aC[rt] = MFMA(Ahi[rt].v, blo.v, aC[rt]);
      }
    }
    float bhv = bh[colH], bcv = bc[colH];
    float pp0[8][2];
    #pragma unroll
    for (int rt = 0; rt < 2; ++rt) {
      #pragma unroll
      for (int r = 0; r < 4; ++r) {
        float h0v = aH[rt][r] + bhv;
        cst[rt * 4 + r] = aC[rt][r] + bcv;
        sh_h[0][(rt * 16 + q * 4 + r) * STR + colH] = (__bf16)h0v;
        pp0[rt * 4 + r][0] = h0v * wo0;
        pp0[rt * 4 + r][1] = h0v * wo1;
      }
    }
    #pragma unroll
    for (int m = 0; m < 8; ++m) {
      pp0[m][0] = row_reduce16(pp0[m][0]);
      pp0[m][1] = row_reduce16(pp0[m][1]);
    }
    if (c16 == 0) {
      #pragma unroll
      for (int rt = 0; rt < 2; ++rt)
        #pragma unroll
        for (int r = 0; r < 4; ++r) {
          sh_pw[0][w][(rt * 16 + q * 4 + r) * 2 + 0] = pp0[rt * 4 + r][0];
          sh_pw[0][w][(rt * 16 + q * 4 + r) * 2 + 1] = pp0[rt * 4 + r][1];
        }
    }
  }
  __syncthreads();   // sA/sB reuse + pw[0] visibility

  // ---- stage static_in = [ball(2), enc(128), pad] (32 rows, stride 168) ----
  for (int e = tid; e < BB * 168; e += 512) {
    int row = e / 168, col = e - row * 168;
    float x = (col < 2) ? ball[(size_t)(rbase + row) * 2 + col]
            : (col < 130) ? enc[(size_t)(rbase + row) * 128 + (col - 2)] : 0.f;
    unsigned short hb = f2bf(x);
    sh_sA[row * 168 + col] = hb;
    sh_sB[row * 168 + col] = f2bf(x - bf2f(hb));
  }
  // virtual pred_{-1} = h0 @ Wo.T + bo (t=0 feedback correction)
  if (tid < BB * 2) {
    float s = (tid & 1) ? bo1 : bo0;
    #pragma unroll
    for (int w2 = 0; w2 < 8; ++w2) s += sh_pw[0][w2][tid];
    sh_p0[tid] = s;
  }
  __syncthreads();

  // ---- gate_static (3-product, K=160, 2 row-tiles) + biases, in REGISTERS ----
  f32x4 gacc[2][4] = {{{0.f,0.f,0.f,0.f},{0.f,0.f,0.f,0.f},{0.f,0.f,0.f,0.f},{0.f,0.f,0.f,0.f}},
                      {{0.f,0.f,0.f,0.f},{0.f,0.f,0.f,0.f},{0.f,0.f,0.f,0.f},{0.f,0.f,0.f,0.f}}};
  #pragma unroll
  for (int kt = 0; kt < 5; ++kt) {
    frag_u Ahi[2], Alo[2];
    #pragma unroll
    for (int rt = 0; rt < 2; ++rt) {
      Ahi[rt].u4 = *(const uint4*)&sh_sA[(rt * 16 + c16) * 168 + kt * 32 + q * 8];
      Alo[rt].u4 = *(const uint4*)&sh_sB[(rt * 16 + c16) * 168 + kt * 32 + q * 8];
    }
    #pragma unroll
    for (int g = 0; g < 4; ++g) {
      frag_u bhi, blo;
      #pragma unroll
      for (int j = 0; j < 8; ++j) {
        int kk = kt * 32 + q * 8 + j;
        float x = (kk < 130) ? W_ih[(size_t)(g * HDIM + colH) * 132 + 2 + kk] : 0.f;
        unsigned short hb = f2bf(x);
        bhi.s[j] = hb;
        blo.s[j] = f2bf(x - bf2f(hb));
      }
      #pragma unroll
      for (int rt = 0; rt < 2; ++rt) {
        gacc[rt][g] = MFMA(Ahi[rt].v, bhi.v, gacc[rt][g]);
        gacc[rt][g] = MFMA(Alo[rt].v, bhi.v, gacc[rt][g]);
        gacc[rt][g] = MFMA(Ahi[rt].v, blo.v, gacc[rt][g]);
      }
    }
  }
  #pragma unroll
  for (int g = 0; g < 4; ++g) {
    int colG = g * HDIM + colH;
    float bb = b_ih[colG] + b_hh[colG] + bo0 * wp0[g] + bo1 * wp1[g];
    #pragma unroll
    for (int rt = 0; rt < 2; ++rt)
      #pragma unroll
      for (int r = 0; r < 4; ++r) gacc[rt][g][r] += bb;
  }

  // ---- time loop: ONE barrier per step; acc seeded via MFMA C-operand ----
  auto body = [&](int t, int rbuf, bool first) {
    const int wbuf = rbuf ^ 1;

    // gates = gacc + h @ W_eff.T  (first kt MFMA consumes gacc as C)
    const __bf16* hp0 = &sh_h[rbuf][c16 * STR];
    const __bf16* hp1 = &sh_h[rbuf][(16 + c16) * STR];
    f32x4 acc[2][4];
    {
      frag_u A0, A1;
      A0.u4 = *(const uint4*)(hp0 + q * 8);
      A1.u4 = *(const uint4*)(hp1 + q * 8);
      #pragma unroll
      for (int g = 0; g < 4; ++g) {
        acc[0][g] = MFMA(A0.v, Wf[g][0].v, gacc[0][g]);
        acc[1][g] = MFMA(A1.v, Wf[g][0].v, gacc[1][g]);
      }
    }
    #pragma unroll
    for (int kt = 1; kt < 4; ++kt) {
      frag_u A0, A1;
      A0.u4 = *(const uint4*)(hp0 + kt * 32 + q * 8);
      A1.u4 = *(const uint4*)(hp1 + kt * 32 + q * 8);
      #pragma unroll
      for (int g = 0; g < 4; ++g) {
        acc[0][g] = MFMA(A0.v, Wf[g][kt].v, acc[0][g]);
        acc[1][g] = MFMA(A1.v, Wf[g][kt].v, acc[1][g]);
      }
    }
    if (first) {  // prev0 = 0: remove the folded pred_{-1} feedback
      #pragma unroll
      for (int rt = 0; rt < 2; ++rt)
        #pragma unroll
        for (int r = 0; r < 4; ++r) {
          float2 p0r = *(const float2*)&sh_p0[(rt * 16 + q * 4 + r) * 2];
          #pragma unroll
          for (int g = 0; g < 4; ++g)
            acc[rt][g][r] -= p0r.x * wp0[g] + p0r.y * wp1[g];
        }
    }

    // elementwise LSTM update; write next h (bf16); pred partials via DPP
    float pp[8][2];
    #pragma unroll
    for (int rt = 0; rt < 2; ++rt) {
      __bf16* hw = &sh_h[wbuf][rt * 16 * STR + colH];
      #pragma unroll
      for (int r = 0; r < 4; ++r) {
        float si = sigm(acc[rt][0][r]);
        float sf = sigm(acc[rt][1][r]);
        float tg = tanh_f(acc[rt][2][r]);
        float so = sigm(acc[rt][3][r]);
        float cv = sf * cst[rt * 4 + r] + si * tg;
        cst[rt * 4 + r] = cv;
        float hv = so * tanh_f(cv);
        hw[(q * 4 + r) * STR] = (__bf16)hv;
        pp[rt * 4 + r][0] = hv * wo0;
        pp[rt * 4 + r][1] = hv * wo1;
      }
    }
    #pragma unroll
    for (int m = 0; m < 8; ++m) {
      pp[m][0] = row_reduce16(pp[m][0]);
      pp[m][1] = row_reduce16(pp[m][1]);
    }
    if (c16 == 0) {
      #pragma unroll
      for (int rt = 0; rt < 2; ++rt)
        #pragma unroll
        for (int r = 0; r < 4; ++r) {
          sh_pw[rbuf][w][(rt * 16 + q * 4 + r) * 2 + 0] = pp[rt * 4 + r][0];
          sh_pw[rbuf][w][(rt * 16 + q * 4 + r) * 2 + 1] = pp[rt * 4 + r][1];
        }
    }
    // lagged combine of pred[t-1] (rotating wave; reads pw[wbuf] = prev step's)
    if (!first && w == (t & 7)) {
      float s = (l & 1) ? bo1 : bo0;
      #pragma unroll
      for (int w2 = 0; w2 < 8; ++w2) s += sh_pw[wbuf][w2][l];
      outp[(size_t)(rbase + (l >> 1)) * (T_FRAMES * 2) + (t - 1) * 2 + (l & 1)] = s;
    }
    __syncthreads();
  };

  body(0, 0, true);    // reads h0 (buf0), writes buf1
  for (int tp = 0; tp < 63; ++tp) {
    body(2 * tp + 1, 1, false);
    body(2 * tp + 2, 0, false);
  }
  body(127, 1, false);

  // final pred (t=127) sits in pw[1]
  if (tid < BB * 2) {
    float s = (tid & 1) ? bo1 : bo0;
    #pragma unroll
    for (int w2 = 0; w2 < 8; ++w2) s += sh_pw[1][w2][tid];
    outp[(size_t)(rbase + (tid >> 1)) * (T_FRAMES * 2) + 127 * 2 + (tid & 1)] = s;
  }
}

extern "C" void kernel_launch(void* const* d_in, const int* in_sizes, int n_in,
                              void* d_out, int out_size, void* d_ws, size_t ws_size,
                              hipStream_t stream) {
  (void)in_sizes; (void)n_in; (void)d_ws; (void)ws_size; (void)out_size;
  const float* ctx  = (const float*)d_in[0];
  const float* enc  = (const float*)d_in[1];
  const float* ball = (const float*)d_in[2];
  // d_in[3] = max_frames (always 128)
  const float* Wh   = (const float*)d_in[4];
  const float* bh   = (const float*)d_in[5];
  const float* Wc   = (const float*)d_in[6];
  const float* bc   = (const float*)d_in[7];
  const float* W_ih = (const float*)d_in[8];
  const float* W_hh = (const float*)d_in[9];
  const float* b_ih = (const float*)d_in[10];
  const float* b_hh = (const float*)d_in[11];
  const float* Wo   = (const float*)d_in[12];
  const float* bo   = (const float*)d_in[13];
  float* outp = (float*)d_out;

  dim3 grid(256), block(512);
  traj_lstm<<<grid, block, 0, stream>>>(ctx, enc, ball, Wh, bh, Wc, bc,
                                        W_ih, W_hh, b_ih, b_hh, Wo, bo, outp);
}

// Round 6
// 343.227 us; speedup vs baseline: 1.5295x; 1.1201x over previous
//
#include <hip/hip_runtime.h>
#include <hip/hip_bf16.h>

// TrajectoryDecoder: B=8192 LSTM, T=128, H=128, CTX=256, IN_DIM=132.
// R6 = R5 (BB=32, 1 block/CU, reg gate_static, MFMA C-seed) with the in-loop
// DPP pred reduce replaced by a SELF-CONTAINED MFMA pred on waves 6/7:
//   pred[t-1] = h_t @ Wo.T computed during step t from the A-frags waves 6/7
//   already load (4 extra chained MFMAs vs zero-padded Wo B-frags), complete
//   in-wave (no cross-wave combine), stored straight to global. Removes
//   16 muls + 64 DPP-adds/lane-step from the VALU pipe and the 4-deep DPP
//   chain from the pre-barrier critical path. Feedback path unchanged.

#define HDIM 128
#define CTX_DIM 256
#define T_FRAMES 128
#define BB 32     // batch rows per block
#define STR 136   // h row stride (elements); 272B rows keep 16B alignment

typedef __bf16 bf16x8 __attribute__((ext_vector_type(8)));
typedef float  f32x4  __attribute__((ext_vector_type(4)));

union frag_u {
  bf16x8 v;
  unsigned short s[8];
  uint4 u4;
};

__device__ __forceinline__ unsigned short f2bf(float x) {
  unsigned u = __builtin_bit_cast(unsigned, x);
  u += 0x7FFFu + ((u >> 16) & 1u);          // RNE to bf16
  return (unsigned short)(u >> 16);
}
__device__ __forceinline__ float bf2f(unsigned short h) {
  unsigned u = ((unsigned)h) << 16;
  return __builtin_bit_cast(float, u);
}
__device__ __forceinline__ float sigm(float x) {
  return __builtin_amdgcn_rcpf(1.f + __expf(-x));
}
__device__ __forceinline__ float tanh_f(float x) {
  return 1.f - 2.f * __builtin_amdgcn_rcpf(1.f + __expf(2.f * x));
}
template<int CTRL>
__device__ __forceinline__ float dpp_mov(float x) {
  return __builtin_bit_cast(float,
    __builtin_amdgcn_mov_dpp(__builtin_bit_cast(int, x), CTRL, 0xF, 0xF, true));
}
// sum over the 16-lane row group (setup-only)
__device__ __forceinline__ float row_reduce16(float v) {
  v += dpp_mov<0xB1>(v);     // quad_perm xor1
  v += dpp_mov<0x4E>(v);     // quad_perm xor2
  v += dpp_mov<0x124>(v);    // row_ror:4
  v += dpp_mov<0x128>(v);    // row_ror:8
  return v;
}

#define MFMA(a, b, c) __builtin_amdgcn_mfma_f32_16x16x32_bf16((a), (b), (c), 0, 0, 0)

__global__ __launch_bounds__(512, 1) void traj_lstm(
    const float* __restrict__ ctx, const float* __restrict__ enc,
    const float* __restrict__ ball,
    const float* __restrict__ Wh, const float* __restrict__ bh,
    const float* __restrict__ Wc, const float* __restrict__ bc,
    const float* __restrict__ W_ih, const float* __restrict__ W_hh,
    const float* __restrict__ b_ih, const float* __restrict__ b_hh,
    const float* __restrict__ Wo, const float* __restrict__ bo,
    float* __restrict__ outp)
{
  __shared__ __align__(16) __bf16 sh_h[2][BB * STR];          // h double buffer (17.4 KB)
  __shared__ __align__(16) unsigned short sh_sA[BB * 264];    // setup staging hi (16.9 KB)
  __shared__ __align__(16) unsigned short sh_sB[BB * 264];    // setup staging lo (16.9 KB)
  __shared__ float sh_pw0[8][BB * 2];     // setup pred partials (2 KB)
  __shared__ float sh_p0[BB * 2];         // virtual pred_{-1} for t=0 correction

  const int tid  = threadIdx.x;
  const int w    = tid >> 6;
  const int l    = tid & 63;
  const int q    = l >> 4;
  const int c16  = l & 15;
  const int colH = w * 16 + c16;
  const int rbase = blockIdx.x * BB;

  const float bo0 = bo[0], bo1 = bo[1];
  const float wo0 = Wo[colH], wo1 = Wo[HDIM + colH];

  // feedback weights per gate (W_prev columns)
  float wp0[4], wp1[4];
  #pragma unroll
  for (int g = 0; g < 4; ++g) {
    wp0[g] = W_ih[(size_t)(g * HDIM + colH) * 132 + 0];
    wp1[g] = W_ih[(size_t)(g * HDIM + colH) * 132 + 1];
  }

  // ---- persistent W_eff fragments: W_hh + wp0*Wo[0] + wp1*Wo[1] (bf16) ----
  frag_u Wf[4][4];                  // [gate][ktile]
  #pragma unroll
  for (int kt = 0; kt < 4; ++kt) {
    const float* w0p = Wo + kt * 32 + q * 8;
    const float* w1p = Wo + HDIM + kt * 32 + q * 8;
    float4 a0 = *(const float4*)w0p, a1 = *(const float4*)(w0p + 4);
    float4 b0 = *(const float4*)w1p, b1 = *(const float4*)(w1p + 4);
    float wo0v[8] = {a0.x, a0.y, a0.z, a0.w, a1.x, a1.y, a1.z, a1.w};
    float wo1v[8] = {b0.x, b0.y, b0.z, b0.w, b1.x, b1.y, b1.z, b1.w};
    #pragma unroll
    for (int g = 0; g < 4; ++g) {
      const float* wr = W_hh + (size_t)(g * HDIM + colH) * HDIM + kt * 32 + q * 8;
      float4 f0 = *(const float4*)wr;
      float4 f1 = *(const float4*)(wr + 4);
      float ff[8] = {f0.x, f0.y, f0.z, f0.w, f1.x, f1.y, f1.z, f1.w};
      #pragma unroll
      for (int j = 0; j < 8; ++j)
        Wf[g][kt].s[j] = f2bf(ff[j] + wp0[g] * wo0v[j] + wp1[g] * wo1v[j]);
    }
  }

  // ---- Wo B-fragments for the in-loop pred MFMA (used by waves 6/7) ----
  // B[k=kt*32+q*8+j][n=c16] = Wo[c16][k] for c16<2, else 0.
  frag_u WoF[4];
  #pragma unroll
  for (int kt = 0; kt < 4; ++kt) {
    #pragma unroll
    for (int j = 0; j < 8; ++j) {
      float x = (c16 < 2) ? Wo[c16 * HDIM + kt * 32 + q * 8 + j] : 0.f;
      WoF[kt].s[j] = f2bf(x);
    }
  }

  // ---- stage context rows (32 rows, hi/lo bf16, stride 264) ----
  for (int e = tid; e < BB * 256; e += 512) {
    int row = e >> 8, col = e & 255;
    float x = ctx[(size_t)(rbase + row) * CTX_DIM + col];
    unsigned short hb = f2bf(x);
    sh_sA[row * 264 + col] = hb;
    sh_sB[row * 264 + col] = f2bf(x - bf2f(hb));
  }
  __syncthreads();

  // ---- h0/c0 = ctx @ Wh.T/Wc.T + bias (3-product split, K=256, 2 row-tiles) ----
  float cst[8];   // [rt*4 + r]
  {
    f32x4 aH[2] = {{0.f,0.f,0.f,0.f},{0.f,0.f,0.f,0.f}};
    f32x4 aC[2] = {{0.f,0.f,0.f,0.f},{0.f,0.f,0.f,0.f}};
    #pragma unroll
    for (int kt = 0; kt < 8; ++kt) {
      frag_u Ahi[2], Alo[2];
      #pragma unroll
      for (int rt = 0; rt < 2; ++rt) {
        Ahi[rt].u4 = *(const uint4*)&sh_sA[(rt * 16 + c16) * 264 + kt * 32 + q * 8];
        Alo[rt].u4 = *(const uint4*)&sh_sB[(rt * 16 + c16) * 264 + kt * 32 + q * 8];
      }
      frag_u bhi, blo;
      {
        const float* wr = Wh + (size_t)colH * CTX_DIM + kt * 32 + q * 8;
        float4 f0 = *(const float4*)wr;
        float4 f1 = *(const float4*)(wr + 4);
        float ff[8] = {f0.x, f0.y, f0.z, f0.w, f1.x, f1.y, f1.z, f1.w};
        #pragma unroll
        for (int j = 0; j < 8; ++j) {
          unsigned short hb = f2bf(ff[j]);
          bhi.s[j] = hb;
          blo.s[j] = f2bf(ff[j] - bf2f(hb));
        }
      }
      #pragma unroll
      for (int rt = 0; rt < 2; ++rt) {
        aH[rt] = MFMA(Ahi[rt].v, bhi.v, aH[rt]);
        aH[rt] = MFMA(Alo[rt].v, bhi.v, aH[rt]);
        aH[rt] = MFMA(Ahi[rt].v, blo.v, aH[rt]);
      }
      {
        const float* wr = Wc + (size_t)colH * CTX_DIM + kt * 32 + q * 8;
        float4 f0 = *(const float4*)wr;
        float4 f1 = *(const float4*)(wr + 4);
        float ff[8] = {f0.x, f0.y, f0.z, f0.w, f1.x, f1.y, f1.z, f1.w};
        #pragma unroll
        for (int j = 0; j < 8; ++j) {
          unsigned short hb = f2bf(ff[j]);
          bhi.s[j] = hb;
          blo.s[j] = f2bf(ff[j] - bf2f(hb));
        }
      }
      #pragma unroll
      for (int rt = 0; rt < 2; ++rt) {
        aC[rt] = MFMA(Ahi[rt].v, bhi.v, aC[rt]);
        aC[rt] = MFMA(Alo[rt].v, bhi.v, aC[rt]);
        aC[rt] = MFMA(Ahi[rt].v, blo.v, aC[rt]);
      }
    }
    float bhv = bh[colH], bcv = bc[colH];
    float pp0[8][2];
    #pragma unroll
    for (int rt = 0; rt < 2; ++rt) {
      #pragma unroll
      for (int r = 0; r < 4; ++r) {
        float h0v = aH[rt][r] + bhv;
        cst[rt * 4 + r] = aC[rt][r] + bcv;
        sh_h[0][(rt * 16 + q * 4 + r) * STR + colH] = (__bf16)h0v;
        pp0[rt * 4 + r][0] = h0v * wo0;
        pp0[rt * 4 + r][1] = h0v * wo1;
      }
    }
    #pragma unroll
    for (int m = 0; m < 8; ++m) {
      pp0[m][0] = row_reduce16(pp0[m][0]);
      pp0[m][1] = row_reduce16(pp0[m][1]);
    }
    if (c16 == 0) {
      #pragma unroll
      for (int rt = 0; rt < 2; ++rt)
        #pragma unroll
        for (int r = 0; r < 4; ++r) {
          sh_pw0[w][(rt * 16 + q * 4 + r) * 2 + 0] = pp0[rt * 4 + r][0];
          sh_pw0[w][(rt * 16 + q * 4 + r) * 2 + 1] = pp0[rt * 4 + r][1];
        }
    }
  }
  __syncthreads();   // sA/sB reuse + pw0 visibility

  // ---- stage static_in = [ball(2), enc(128), pad] (32 rows, stride 168) ----
  for (int e = tid; e < BB * 168; e += 512) {
    int row = e / 168, col = e - row * 168;
    float x = (col < 2) ? ball[(size_t)(rbase + row) * 2 + col]
            : (col < 130) ? enc[(size_t)(rbase + row) * 128 + (col - 2)] : 0.f;
    unsigned short hb = f2bf(x);
    sh_sA[row * 168 + col] = hb;
    sh_sB[row * 168 + col] = f2bf(x - bf2f(hb));
  }
  // virtual pred_{-1} = h0 @ Wo.T + bo (t=0 feedback correction)
  if (tid < BB * 2) {
    float s = (tid & 1) ? bo1 : bo0;
    #pragma unroll
    for (int w2 = 0; w2 < 8; ++w2) s += sh_pw0[w2][tid];
    sh_p0[tid] = s;
  }
  __syncthreads();

  // ---- gate_static (3-product, K=160, 2 row-tiles) + biases, in REGISTERS ----
  f32x4 gacc[2][4] = {{{0.f,0.f,0.f,0.f},{0.f,0.f,0.f,0.f},{0.f,0.f,0.f,0.f},{0.f,0.f,0.f,0.f}},
                      {{0.f,0.f,0.f,0.f},{0.f,0.f,0.f,0.f},{0.f,0.f,0.f,0.f},{0.f,0.f,0.f,0.f}}};
  #pragma unroll
  for (int kt = 0; kt < 5; ++kt) {
    frag_u Ahi[2], Alo[2];
    #pragma unroll
    for (int rt = 0; rt < 2; ++rt) {
      Ahi[rt].u4 = *(const uint4*)&sh_sA[(rt * 16 + c16) * 168 + kt * 32 + q * 8];
      Alo[rt].u4 = *(const uint4*)&sh_sB[(rt * 16 + c16) * 168 + kt * 32 + q * 8];
    }
    #pragma unroll
    for (int g = 0; g < 4; ++g) {
      frag_u bhi, blo;
      #pragma unroll
      for (int j = 0; j < 8; ++j) {
        int kk = kt * 32 + q * 8 + j;
        float x = (kk < 130) ? W_ih[(size_t)(g * HDIM + colH) * 132 + 2 + kk] : 0.f;
        unsigned short hb = f2bf(x);
        bhi.s[j] = hb;
        blo.s[j] = f2bf(x - bf2f(hb));
      }
      #pragma unroll
      for (int rt = 0; rt < 2; ++rt) {
        gacc[rt][g] = MFMA(Ahi[rt].v, bhi.v, gacc[rt][g]);
        gacc[rt][g] = MFMA(Alo[rt].v, bhi.v, gacc[rt][g]);
        gacc[rt][g] = MFMA(Ahi[rt].v, blo.v, gacc[rt][g]);
      }
    }
  }
  #pragma unroll
  for (int g = 0; g < 4; ++g) {
    int colG = g * HDIM + colH;
    float bb = b_ih[colG] + b_hh[colG] + bo0 * wp0[g] + bo1 * wp1[g];
    #pragma unroll
    for (int rt = 0; rt < 2; ++rt)
      #pragma unroll
      for (int r = 0; r < 4; ++r) gacc[rt][g][r] += bb;
  }

  // ---- time loop: ONE barrier per step; pred via MFMA on waves 6/7 ----
  auto body = [&](int t, int rbuf, bool first) {
    const int wbuf = rbuf ^ 1;

    const __bf16* hp0 = &sh_h[rbuf][c16 * STR];
    const __bf16* hp1 = &sh_h[rbuf][(16 + c16) * STR];
    f32x4 acc[2][4];
    f32x4 accP = {0.f, 0.f, 0.f, 0.f};
    {
      frag_u A0, A1;
      A0.u4 = *(const uint4*)(hp0 + q * 8);
      A1.u4 = *(const uint4*)(hp1 + q * 8);
      #pragma unroll
      for (int g = 0; g < 4; ++g) {
        acc[0][g] = MFMA(A0.v, Wf[g][0].v, gacc[0][g]);
        acc[1][g] = MFMA(A1.v, Wf[g][0].v, gacc[1][g]);
      }
      if (!first && w >= 6)
        accP = MFMA((w == 6 ? A0.v : A1.v), WoF[0].v, accP);
    }
    #pragma unroll
    for (int kt = 1; kt < 4; ++kt) {
      frag_u A0, A1;
      A0.u4 = *(const uint4*)(hp0 + kt * 32 + q * 8);
      A1.u4 = *(const uint4*)(hp1 + kt * 32 + q * 8);
      #pragma unroll
      for (int g = 0; g < 4; ++g) {
        acc[0][g] = MFMA(A0.v, Wf[g][kt].v, acc[0][g]);
        acc[1][g] = MFMA(A1.v, Wf[g][kt].v, acc[1][g]);
      }
      if (!first && w >= 6)
        accP = MFMA((w == 6 ? A0.v : A1.v), WoF[kt].v, accP);
    }
    if (first) {  // prev0 = 0: remove the folded pred_{-1} feedback
      #pragma unroll
      for (int rt = 0; rt < 2; ++rt)
        #pragma unroll
        for (int r = 0; r < 4; ++r) {
          float2 p0r = *(const float2*)&sh_p0[(rt * 16 + q * 4 + r) * 2];
          #pragma unroll
          for (int g = 0; g < 4; ++g)
            acc[rt][g][r] -= p0r.x * wp0[g] + p0r.y * wp1[g];
        }
    }
    // store pred[t-1] (complete in-wave: D[m=q*4+r][n=c16], n<2 are real dims)
    if (!first && w >= 6 && c16 < 2) {
      const int m0 = (w - 6) * 16 + q * 4;
      const float bov = c16 ? bo1 : bo0;
      #pragma unroll
      for (int r = 0; r < 4; ++r)
        outp[(size_t)(rbase + m0 + r) * (T_FRAMES * 2) + (t - 1) * 2 + c16] = accP[r] + bov;
    }

    // elementwise LSTM update; write next h (bf16)
    #pragma unroll
    for (int rt = 0; rt < 2; ++rt) {
      __bf16* hw = &sh_h[wbuf][rt * 16 * STR + colH];
      #pragma unroll
      for (int r = 0; r < 4; ++r) {
        float si = sigm(acc[rt][0][r]);
        float sf = sigm(acc[rt][1][r]);
        float tg = tanh_f(acc[rt][2][r]);
        float so = sigm(acc[rt][3][r]);
        float cv = sf * cst[rt * 4 + r] + si * tg;
        cst[rt * 4 + r] = cv;
        float hv = so * tanh_f(cv);
        hw[(q * 4 + r) * STR] = (__bf16)hv;
      }
    }
    __syncthreads();
  };

  body(0, 0, true);    // reads h0 (buf0), writes buf1
  for (int tp = 0; tp < 63; ++tp) {
    body(2 * tp + 1, 1, false);
    body(2 * tp + 2, 0, false);
  }
  body(127, 1, false);   // stores pred[126]; final h_128 lands in buf 0

  // ---- epilogue: pred[127] from final h (buf 0), waves 6/7 ----
  if (w >= 6) {
    const __bf16* hp = &sh_h[0][((w - 6) * 16 + c16) * STR];
    f32x4 accP = {0.f, 0.f, 0.f, 0.f};
    #pragma unroll
    for (int kt = 0; kt < 4; ++kt) {
      frag_u A;
      A.u4 = *(const uint4*)(hp + kt * 32 + q * 8);
      accP = MFMA(A.v, WoF[kt].v, accP);
    }
    if (c16 < 2) {
      const int m0 = (w - 6) * 16 + q * 4;
      const float bov = c16 ? bo1 : bo0;
      #pragma unroll
      for (int r = 0; r < 4; ++r)
        outp[(size_t)(rbase + m0 + r) * (T_FRAMES * 2) + 127 * 2 + c16] = accP[r] + bov;
    }
  }
}

extern "C" void kernel_launch(void* const* d_in, const int* in_sizes, int n_in,
                              void* d_out, int out_size, void* d_ws, size_t ws_size,
                              hipStream_t stream) {
  (void)in_sizes; (void)n_in; (void)d_ws; (void)ws_size; (void)out_size;
  const float* ctx  = (const float*)d_in[0];
  const float* enc  = (const float*)d_in[1];
  const float* ball = (const float*)d_in[2];
  // d_in[3] = max_frames (always 128)
  const float* Wh   = (const float*)d_in[4];
  const float* bh   = (const float*)d_in[5];
  const float* Wc   = (const float*)d_in[6];
  const float* bc   = (const float*)d_in[7];
  const float* W_ih = (const float*)d_in[8];
  const float* W_hh = (const float*)d_in[9];
  const float* b_ih = (const float*)d_in[10];
  const float* b_hh = (const float*)d_in[11];
  const float* Wo   = (const float*)d_in[12];
  const float* bo   = (const float*)d_in[13];
  float* outp = (float*)d_out;

  dim3 grid(256), block(512);
  traj_lstm<<<grid, block, 0, stream>>>(ctx, enc, ball, Wh, bh, Wc, bc,
                                        W_ih, W_hh, b_ih, b_hh, Wo, bo, outp);
}